// Round 2
// baseline (2756.413 us; speedup 1.0000x reference)
//
#include <hip/hip_runtime.h>
#include <math.h>

typedef __attribute__((ext_vector_type(8))) short bf16x8;
typedef __attribute__((ext_vector_type(4))) float floatx4;
typedef __attribute__((ext_vector_type(4))) unsigned short ushort4v;

typedef __attribute__((address_space(1))) void as1_void;
typedef __attribute__((address_space(3))) void as3_void;

static __device__ __forceinline__ unsigned short f2b(float f) {
    union { float f; unsigned u; } v; v.f = f;
    unsigned r = v.u + 0x7fffu + ((v.u >> 16) & 1u);
    return (unsigned short)(r >> 16);
}
static __device__ __forceinline__ float b2f(unsigned short h) {
    union { unsigned u; float f; } v; v.u = ((unsigned)h) << 16;
    return v.f;
}

// ---------------------------------------------------------------------------
// Batched GEMM: C = A(bf16 [M][K], row stride lda) x Bt(bf16 [N][K], row
// stride ldb)^T, fp32 accumulate. Per-z offsets: zq=z/zdiv, zr=z%zdiv.
// mode 0: Cf = acc+bias | 1: Cf += acc+bias | 2: Cb = bf16(acc+bias)
// mode 3: Cb = bf16(gelu_exact(acc+bias))
// Grid: (N/128, M/128, Z), block 256. K % 32 == 0.
// ---------------------------------------------------------------------------
__global__ __launch_bounds__(256) void gemm_bf16(
    const unsigned short* __restrict__ A,
    const unsigned short* __restrict__ Bt,
    float* __restrict__ Cf, unsigned short* __restrict__ Cb,
    const float* __restrict__ bias,
    int K, int lda, int ldb, int ldc,
    int zdiv, long a_s1, long a_s2, long b_s1, long b_s2, long c_s1, long c_s2,
    int mode)
{
    // chunk-major LDS: As[q][row][8] (q = k-chunk of 8 bf16), global_load_lds-compatible
    __shared__ unsigned short As[4 * 128 * 8];
    __shared__ unsigned short Bs[4 * 128 * 8];

    const int tid  = threadIdx.x;
    const int wid  = tid >> 6;
    const int lane = tid & 63;
    const int q    = lane >> 4;
    const int r    = lane & 15;

    const int z  = blockIdx.z;
    const int zq = z / zdiv, zr = z % zdiv;
    const long offC = (long)zq * c_s1 + (long)zr * c_s2;

    const int m0 = blockIdx.y * 128;
    const int n0 = blockIdx.x * 128;

    const unsigned short* Ab = A  + (long)zq * a_s1 + (long)zr * a_s2 + (long)m0 * lda;
    const unsigned short* Bb = Bt + (long)zq * b_s1 + (long)zr * b_s2 + (long)n0 * ldb;

    const int wr = (wid >> 1) << 6;
    const int wc = (wid & 1) << 6;

    floatx4 acc[4][4];
    #pragma unroll
    for (int i = 0; i < 4; ++i)
        #pragma unroll
        for (int j = 0; j < 4; ++j)
            acc[i][j] = (floatx4){0.f, 0.f, 0.f, 0.f};

    const int qc = wid;   // wave wid stages k-chunk wid for A and B
    unsigned short* lA0 = &As[(qc * 128 +  0) * 8];
    unsigned short* lA1 = &As[(qc * 128 + 64) * 8];
    unsigned short* lB0 = &Bs[(qc * 128 +  0) * 8];
    unsigned short* lB1 = &Bs[(qc * 128 + 64) * 8];

    const int nk = K >> 5;
    for (int kt = 0; kt < nk; ++kt) {
        const int kofs = (kt << 5) + (qc << 3);
        __syncthreads();
        const unsigned short* gA0 = Ab + (long)lane        * lda + kofs;
        const unsigned short* gA1 = Ab + (long)(lane + 64) * lda + kofs;
        const unsigned short* gB0 = Bb + (long)lane        * ldb + kofs;
        const unsigned short* gB1 = Bb + (long)(lane + 64) * ldb + kofs;
        __builtin_amdgcn_global_load_lds((as1_void*)(void*)gA0, (as3_void*)lA0, 16, 0, 0);
        __builtin_amdgcn_global_load_lds((as1_void*)(void*)gA1, (as3_void*)lA1, 16, 0, 0);
        __builtin_amdgcn_global_load_lds((as1_void*)(void*)gB0, (as3_void*)lB0, 16, 0, 0);
        __builtin_amdgcn_global_load_lds((as1_void*)(void*)gB1, (as3_void*)lB1, 16, 0, 0);
        __syncthreads();

        bf16x8 av[4], bv[4];
        #pragma unroll
        for (int i = 0; i < 4; ++i)
            av[i] = *(const bf16x8*)&As[(q * 128 + wr + i * 16 + r) * 8];
        #pragma unroll
        for (int j = 0; j < 4; ++j)
            bv[j] = *(const bf16x8*)&Bs[(q * 128 + wc + j * 16 + r) * 8];
        #pragma unroll
        for (int i = 0; i < 4; ++i)
            #pragma unroll
            for (int j = 0; j < 4; ++j)
                acc[i][j] = __builtin_amdgcn_mfma_f32_16x16x32_bf16(av[i], bv[j], acc[i][j], 0, 0, 0);
    }

    // C layout: row = q*4 + reg, col = r (verified m89/m91)
    #pragma unroll
    for (int i = 0; i < 4; ++i) {
        const int gr0 = m0 + wr + i * 16 + q * 4;
        #pragma unroll
        for (int j = 0; j < 4; ++j) {
            const int gc = n0 + wc + j * 16 + r;
            const float bvl = bias ? bias[gc] : 0.0f;
            #pragma unroll
            for (int rr = 0; rr < 4; ++rr) {
                const long cidx = offC + (long)(gr0 + rr) * ldc + gc;
                float v = acc[i][j][rr] + bvl;
                if (mode == 0) {
                    Cf[cidx] = v;
                } else if (mode == 1) {
                    Cf[cidx] += v;
                } else if (mode == 2) {
                    Cb[cidx] = f2b(v);
                } else {
                    Cb[cidx] = f2b(0.5f * v * (1.0f + erff(v * 0.70710678118654752f)));
                }
            }
        }
    }
}

// fp32 [R][C] -> bf16 [C][R], 32x32 LDS tile transpose
__global__ void transpose_cast_f32(const float* __restrict__ in, unsigned short* __restrict__ out,
                                   int R, int C)
{
    __shared__ float t[32][33];
    const int c0 = blockIdx.x * 32, r0 = blockIdx.y * 32;
    const int tx = threadIdx.x, ty = threadIdx.y;
    #pragma unroll
    for (int i = 0; i < 4; ++i)
        t[ty + i * 8][tx] = in[(long)(r0 + ty + i * 8) * C + c0 + tx];
    __syncthreads();
    #pragma unroll
    for (int i = 0; i < 4; ++i)
        out[(long)(c0 + ty + i * 8) * R + r0 + tx] = f2b(t[tx][ty + i * 8]);
}

// V slice of qkv_b [2048][3072] (cols 2048 + h*256 + d) -> vT [h][d][m]
__global__ void transpose_v(const unsigned short* __restrict__ qkv, unsigned short* __restrict__ vT)
{
    __shared__ unsigned short t[32][33];
    const int hh = blockIdx.z;
    const int d0 = blockIdx.x * 32, m0 = blockIdx.y * 32;
    const int tx = threadIdx.x, ty = threadIdx.y;
    const unsigned short* ip = qkv + 2048 + hh * 256;
    unsigned short* op = vT + (long)hh * 524288;
    #pragma unroll
    for (int i = 0; i < 4; ++i)
        t[ty + i * 8][tx] = ip[(long)(m0 + ty + i * 8) * 3072 + d0 + tx];
    __syncthreads();
    #pragma unroll
    for (int i = 0; i < 4; ++i)
        op[(long)(d0 + ty + i * 8) * 2048 + m0 + tx] = t[tx][ty + i * 8];
}

__global__ void cast_f32_bf16(const float* __restrict__ in, unsigned short* __restrict__ out)
{
    const long i = (long)blockIdx.x * 256 + threadIdx.x;   // one float4 each
    const float4 v = ((const float4*)in)[i];
    ushort4v o;
    o[0] = f2b(v.x); o[1] = f2b(v.y); o[2] = f2b(v.z); o[3] = f2b(v.w);
    ((ushort4v*)out)[i] = o;
}

__global__ void zero_f32(float* __restrict__ p)
{
    p[blockIdx.x * 256 + threadIdx.x] = 0.0f;
}

// LayerNorm over D=1024, one block per token, writes bf16
__global__ __launch_bounds__(256) void ln_kernel(const float* __restrict__ h,
    const float* __restrict__ g, const float* __restrict__ bta,
    unsigned short* __restrict__ out)
{
    const int tok = blockIdx.x;
    const float4 v = ((const float4*)(h + (long)tok * 1024))[threadIdx.x];
    float s  = v.x + v.y + v.z + v.w;
    float s2 = v.x * v.x + v.y * v.y + v.z * v.z + v.w * v.w;
    #pragma unroll
    for (int off = 32; off > 0; off >>= 1) {
        s  += __shfl_xor(s, off);
        s2 += __shfl_xor(s2, off);
    }
    __shared__ float rs[4], rs2[4];
    const int wid = threadIdx.x >> 6, lane = threadIdx.x & 63;
    if (lane == 0) { rs[wid] = s; rs2[wid] = s2; }
    __syncthreads();
    s  = rs[0] + rs[1] + rs[2] + rs[3];
    s2 = rs2[0] + rs2[1] + rs2[2] + rs2[3];
    const float mu = s * (1.0f / 1024.0f);
    float var = s2 * (1.0f / 1024.0f) - mu * mu;
    var = fmaxf(var, 0.0f);
    const float rsg = 1.0f / sqrtf(var + 1e-5f);
    const float4 gv = ((const float4*)g)[threadIdx.x];
    const float4 bv = ((const float4*)bta)[threadIdx.x];
    ushort4v o;
    o[0] = f2b((v.x - mu) * rsg * gv.x + bv.x);
    o[1] = f2b((v.y - mu) * rsg * gv.y + bv.y);
    o[2] = f2b((v.z - mu) * rsg * gv.z + bv.z);
    o[3] = f2b((v.w - mu) * rsg * gv.w + bv.w);
    *(ushort4v*)&out[(long)tok * 1024 + threadIdx.x * 4] = o;
}

// RoPE in-place on bf16 qkv_b [2048][3072] (q: 0..1023, k: 1024..2047)
__global__ __launch_bounds__(256) void rope_kernel(unsigned short* __restrict__ qkv,
                                                   const int* __restrict__ pos)
{
    const int tok = blockIdx.x;
    const float p = (float)pos[tok];
    unsigned short* base = qkv + (long)tok * 3072;
    #pragma unroll
    for (int it = 0; it < 2; ++it) {
        const int idx = threadIdx.x + it * 256;  // (head, d<128)
        const int hh = idx >> 7, d = idx & 127;
        const float inv = powf(10000.0f, -(float)d * (1.0f / 128.0f));
        const float ang = p * inv;
        const float c = cosf(ang), s = sinf(ang);
        unsigned short* qp = base + hh * 256 + d;
        {
            const float x1 = b2f(qp[0]), x2 = b2f(qp[128]);
            qp[0]   = f2b(x1 * c - x2 * s);
            qp[128] = f2b(x1 * s + x2 * c);
        }
        unsigned short* kp = qp + 1024;
        {
            const float x1 = b2f(kp[0]), x2 = b2f(kp[128]);
            kp[0]   = f2b(x1 * c - x2 * s);
            kp[128] = f2b(x1 * s + x2 * c);
        }
    }
}

// Row softmax, in-place bf16, scale 1/16; mask_row is this batch's mask.
// Grid: 4*2048 rows, block 256, 8 elems/thread.
__global__ __launch_bounds__(256) void softmax_kernel(unsigned short* __restrict__ sc,
                                                      const float* __restrict__ mrow)
{
    unsigned short* row = sc + (long)blockIdx.x * 2048;
    const int t = threadIdx.x;

    float v[8];
    const ushort4v u0 = *(const ushort4v*)&row[t * 8];
    const ushort4v u1 = *(const ushort4v*)&row[t * 8 + 4];
    #pragma unroll
    for (int i = 0; i < 4; ++i) { v[i] = b2f(u0[i]); v[4 + i] = b2f(u1[i]); }

    float mx = -3.0e38f;
    #pragma unroll
    for (int i = 0; i < 8; ++i) {
        const float m = mrow[t * 8 + i];
        v[i] = (m == 0.0f) ? -3.0e38f : v[i] * 0.0625f;
        mx = fmaxf(mx, v[i]);
    }
    #pragma unroll
    for (int off = 32; off > 0; off >>= 1) mx = fmaxf(mx, __shfl_xor(mx, off));
    __shared__ float rmx[4], rsm[4];
    const int wid = t >> 6, lane = t & 63;
    if (lane == 0) rmx[wid] = mx;
    __syncthreads();
    mx = fmaxf(fmaxf(rmx[0], rmx[1]), fmaxf(rmx[2], rmx[3]));

    float s = 0.0f;
    #pragma unroll
    for (int i = 0; i < 8; ++i) { v[i] = expf(v[i] - mx); s += v[i]; }
    #pragma unroll
    for (int off = 32; off > 0; off >>= 1) s += __shfl_xor(s, off);
    if (lane == 0) rsm[wid] = s;
    __syncthreads();
    s = rsm[0] + rsm[1] + rsm[2] + rsm[3];
    const float invs = (s > 0.0f) ? 1.0f / s : 0.0f;

    ushort4v o0, o1;
    #pragma unroll
    for (int i = 0; i < 4; ++i) { o0[i] = f2b(v[i] * invs); o1[i] = f2b(v[4 + i] * invs); }
    *(ushort4v*)&row[t * 8]     = o0;
    *(ushort4v*)&row[t * 8 + 4] = o1;
}

// lengths = sum(mask[b]); out[b] = len>0 ? h[b, len-1] : start_state
__global__ __launch_bounds__(256) void gather_kernel(const float* __restrict__ h,
    const float* __restrict__ mask, const float* __restrict__ ss, float* __restrict__ out)
{
    const int b = blockIdx.x;
    const float* mrow = mask + b * 2048;
    const int t = threadIdx.x;
    float s = 0.0f;
    #pragma unroll
    for (int i = 0; i < 8; ++i) s += mrow[t * 8 + i];
    #pragma unroll
    for (int off = 32; off > 0; off >>= 1) s += __shfl_xor(s, off);
    __shared__ float red[4];
    if ((t & 63) == 0) red[t >> 6] = s;
    __syncthreads();
    const float len = red[0] + red[1] + red[2] + red[3];
    const int L = (int)len;
    const int last = (L > 0) ? (L - 1) : 0;
    const bool has = len > 0.0f;
    const float* src = has ? (h + ((long)b * 2048 + last) * 1024) : ss;
    #pragma unroll
    for (int i = 0; i < 4; ++i) {
        const int d = t + i * 256;
        out[b * 1024 + d] = src[d];
    }
}

// ---------------------------------------------------------------------------
extern "C" void kernel_launch(void* const* d_in, const int* in_sizes, int n_in,
                              void* d_out, int out_size, void* d_ws, size_t ws_size,
                              hipStream_t stream)
{
    (void)in_sizes; (void)n_in; (void)out_size;
    const float* x      = (const float*)d_in[0];
    const int*   pos    = (const int*)d_in[1];
    const float* mask   = (const float*)d_in[2];
    const float* in_w   = (const float*)d_in[3];
    const float* in_b   = (const float*)d_in[4];
    const float* qkv_w  = (const float*)d_in[5];
    const float* o_w    = (const float*)d_in[6];
    const float* ln1_g  = (const float*)d_in[7];
    const float* ln1_b  = (const float*)d_in[8];
    const float* ffn_w1 = (const float*)d_in[9];
    const float* ffn_b1 = (const float*)d_in[10];
    const float* ffn_w2 = (const float*)d_in[11];
    const float* ffn_b2 = (const float*)d_in[12];
    const float* ln2_g  = (const float*)d_in[13];
    const float* ln2_b  = (const float*)d_in[14];
    const float* sstate = (const float*)d_in[15];
    float* out = (float*)d_out;

    // ---- workspace layout, ~137 MB with aggressive reuse ----
    const size_t NEED = 143654912ull;
    if (ws_size < NEED) {           // ws_size is constant across calls -> capture-safe
        zero_f32<<<16, 256, 0, stream>>>(out);   // visible clean failure instead of a fault
        return;
    }
    char* w = (char*)d_ws;
    unsigned short* wt_in  = (unsigned short*)(w);               // [1024][512]      1.0 MB
    unsigned short* wt_qkv = (unsigned short*)(w + 1048576);     // [3072][1024]/lyr 6.3 MB
    unsigned short* wt_o   = (unsigned short*)(w + 7340032);     // [1024][1024]/lyr 2.1 MB
    unsigned short* wt_f1  = (unsigned short*)(w + 9437184);     // [4096][1024]/lyr 8.4 MB
    unsigned short* wt_f2  = (unsigned short*)(w + 17825792);    // [1024][4096]/lyr 8.4 MB
    float*          hbuf   = (float*)(w + 26214400);             // [8192][1024] f32 33.5 MB
    unsigned short* xn_bf  = (unsigned short*)(w + 59768832);    // [8192][1024]     16.8 MB
    unsigned short* ao_bf  = (unsigned short*)(w + 76546048);    // [8192][1024]     16.8 MB (x_bf aliases)
    unsigned short* qkv_b  = (unsigned short*)(w + 93323264);    // [2048][3072]/b   12.6 MB
    unsigned short* vT_b   = (unsigned short*)(w + 105906176);   // [4][256][2048]/b  4.2 MB
    unsigned short* scmid  = (unsigned short*)(w + 110100480);   // [4][2048][2048]  33.5 MB (mid half aliases)
    unsigned short* x_bf   = ao_bf;                              // [8192][512], dead before ao is live

    const dim3 tb(32, 8);

    transpose_cast_f32<<<dim3(32, 16), tb, 0, stream>>>(in_w, wt_in, 512, 1024);
    cast_f32_bf16<<<4096, 256, 0, stream>>>(x, x_bf);

    // h = x @ in_w + in_b   (f32)
    gemm_bf16<<<dim3(8, 64, 1), 256, 0, stream>>>(x_bf, wt_in, hbuf, nullptr, in_b,
        512, 512, 512, 1024, 1, 0, 0, 0, 0, 0, 0, 0);

    for (int l = 0; l < 2; ++l) {
        // per-layer weight transposes into reused slots
        transpose_cast_f32<<<dim3(96, 32),  tb, 0, stream>>>(qkv_w  + (long)l * 3145728, wt_qkv, 1024, 3072);
        transpose_cast_f32<<<dim3(32, 32),  tb, 0, stream>>>(o_w    + (long)l * 1048576, wt_o,   1024, 1024);
        transpose_cast_f32<<<dim3(128, 32), tb, 0, stream>>>(ffn_w1 + (long)l * 4194304, wt_f1,  1024, 4096);
        transpose_cast_f32<<<dim3(32, 128), tb, 0, stream>>>(ffn_w2 + (long)l * 4194304, wt_f2,  4096, 1024);

        ln_kernel<<<8192, 256, 0, stream>>>(hbuf, ln1_g + l * 1024, ln1_b + l * 1024, xn_bf);

        for (int b = 0; b < 4; ++b) {
            // qkv_b = LN1(h)[b] @ qkv_w  (bf16)
            gemm_bf16<<<dim3(24, 16, 1), 256, 0, stream>>>(xn_bf + (long)b * 2097152, wt_qkv,
                nullptr, qkv_b, nullptr, 1024, 1024, 1024, 3072, 1, 0, 0, 0, 0, 0, 0, 2);
            rope_kernel<<<2048, 256, 0, stream>>>(qkv_b, pos + b * 2048);
            transpose_v<<<dim3(8, 64, 4), tb, 0, stream>>>(qkv_b, vT_b);
            // scores[h] = q @ k^T  (raw; softmax applies 1/16)
            gemm_bf16<<<dim3(16, 16, 4), 256, 0, stream>>>(qkv_b, qkv_b + 1024,
                nullptr, scmid, nullptr, 256, 3072, 3072, 2048,
                1, 256l, 0, 256l, 0, 4194304l, 0, 2);
            softmax_kernel<<<8192, 256, 0, stream>>>(scmid, mask + b * 2048);
            // ao[b][m][h*256+d] = P @ V
            gemm_bf16<<<dim3(2, 16, 4), 256, 0, stream>>>(scmid, vT_b,
                nullptr, ao_bf + (long)b * 2097152, nullptr, 2048, 2048, 2048, 1024,
                1, 4194304l, 0, 524288l, 0, 256l, 0, 2);
        }
        // h += attn_out @ o_w
        gemm_bf16<<<dim3(8, 64, 1), 256, 0, stream>>>(ao_bf, wt_o,
            hbuf, nullptr, nullptr, 1024, 1024, 1024, 1024, 1, 0, 0, 0, 0, 0, 0, 1);

        ln_kernel<<<8192, 256, 0, stream>>>(hbuf, ln2_g + l * 1024, ln2_b + l * 1024, xn_bf);

        for (int half = 0; half < 2; ++half) {
            // mid = gelu(LN2(h)[half] @ w1 + b1)  (bf16, aliases score buffer)
            gemm_bf16<<<dim3(32, 32, 1), 256, 0, stream>>>(xn_bf + (long)half * 4194304, wt_f1,
                nullptr, scmid, ffn_b1 + l * 4096, 1024, 1024, 1024, 4096, 1, 0, 0, 0, 0, 0, 0, 3);
            // h[half] += mid @ w2 + b2
            gemm_bf16<<<dim3(8, 32, 1), 256, 0, stream>>>(scmid, wt_f2,
                hbuf + (long)half * 4194304, nullptr, ffn_b2 + l * 1024,
                4096, 4096, 4096, 1024, 1, 0, 0, 0, 0, 0, 0, 1);
        }
    }

    gather_kernel<<<4, 256, 0, stream>>>(hbuf, mask, sstate, out);
}

// Round 3
// 2272.792 us; speedup vs baseline: 1.2128x; 1.2128x over previous
//
#include <hip/hip_runtime.h>
#include <math.h>

typedef __attribute__((ext_vector_type(8))) short bf16x8;
typedef __attribute__((ext_vector_type(4))) float floatx4;
typedef __attribute__((ext_vector_type(4))) unsigned short ushort4v;

typedef __attribute__((address_space(1))) void as1_void;
typedef __attribute__((address_space(3))) void as3_void;

static __device__ __forceinline__ unsigned short f2b(float f) {
    union { float f; unsigned u; } v; v.f = f;
    unsigned r = v.u + 0x7fffu + ((v.u >> 16) & 1u);
    return (unsigned short)(r >> 16);
}
static __device__ __forceinline__ float b2f(unsigned short h) {
    union { unsigned u; float f; } v; v.u = ((unsigned)h) << 16;
    return v.f;
}

// ---------------------------------------------------------------------------
// Pipelined batched GEMM: C = A(bf16 [M][K], lda) x Bt(bf16 [N][K], ldb)^T,
// fp32 accumulate, TxT tile (T=128 or 64), BK=32, double-buffered LDS with
// global_load_lds prefetch issued BEFORE compute, raw s_barrier + precise
// vmcnt so the prefetch stays in flight across the barrier (no vmcnt(0) drain).
// mode 0: Cf = acc+bias | 1: Cf += acc+bias | 2: Cb = bf16(acc+bias)
// mode 3: Cb = bf16(gelu_exact(acc+bias))
// Grid: (N/T, M/T, Z), block 256. K % 32 == 0.
// ---------------------------------------------------------------------------
template<int T>
__global__ __launch_bounds__(256) void gemm_bf16(
    const unsigned short* __restrict__ A,
    const unsigned short* __restrict__ Bt,
    float* __restrict__ Cf, unsigned short* __restrict__ Cb,
    const float* __restrict__ bias,
    int K, int lda, int ldb, int ldc,
    int zdiv, long a_s1, long a_s2, long b_s1, long b_s2, long c_s1, long c_s2,
    int mode)
{
    constexpr int F  = T / 32;   // 16x16 frags per wave dim (4 or 2)
    constexpr int NR = T / 64;   // staging insts per matrix per wave (2 or 1)

    // chunk-major LDS: As[buf][q][row][8] (q = k-chunk of 8 bf16)
    __shared__ unsigned short As[2][4 * T * 8];
    __shared__ unsigned short Bs[2][4 * T * 8];

    const int tid  = threadIdx.x;
    const int wid  = tid >> 6;
    const int lane = tid & 63;
    const int q    = lane >> 4;
    const int r    = lane & 15;

    const int z  = blockIdx.z;
    const int zq = z / zdiv, zr = z % zdiv;
    const long offC = (long)zq * c_s1 + (long)zr * c_s2;

    const int m0 = blockIdx.y * T;
    const int n0 = blockIdx.x * T;

    const unsigned short* Ab = A  + (long)zq * a_s1 + (long)zr * a_s2 + (long)m0 * lda;
    const unsigned short* Bb = Bt + (long)zq * b_s1 + (long)zr * b_s2 + (long)n0 * ldb;

    const int wr = (wid >> 1) * (T / 2);
    const int wc = (wid & 1)  * (T / 2);

    floatx4 acc[F][F];
    #pragma unroll
    for (int i = 0; i < F; ++i)
        #pragma unroll
        for (int j = 0; j < F; ++j)
            acc[i][j] = (floatx4){0.f, 0.f, 0.f, 0.f};

    const int qc = wid;   // this wave stages k-chunk `wid` of both tiles
    const int nk = K >> 5;

    auto stage = [&](int kt, int buf) {
        const int kofs = (kt << 5) + (qc << 3);
        #pragma unroll
        for (int rb = 0; rb < NR; ++rb)
            __builtin_amdgcn_global_load_lds(
                (as1_void*)(void*)(Ab + (long)(lane + rb * 64) * lda + kofs),
                (as3_void*)&As[buf][(qc * T + rb * 64) * 8], 16, 0, 0);
        #pragma unroll
        for (int rb = 0; rb < NR; ++rb)
            __builtin_amdgcn_global_load_lds(
                (as1_void*)(void*)(Bb + (long)(lane + rb * 64) * ldb + kofs),
                (as3_void*)&Bs[buf][(qc * T + rb * 64) * 8], 16, 0, 0);
    };

    stage(0, 0);
    for (int kt = 0; kt < nk; ++kt) {
        const int cur = kt & 1;
        if (kt + 1 < nk) {
            stage(kt + 1, cur ^ 1);          // prefetch next tile (stays in flight)
            if constexpr (NR == 2) asm volatile("s_waitcnt vmcnt(4)" ::: "memory");
            else                   asm volatile("s_waitcnt vmcnt(2)" ::: "memory");
        } else {
            asm volatile("s_waitcnt vmcnt(0)" ::: "memory");
        }
        asm volatile("s_barrier" ::: "memory");   // tile kt resident for all waves

        bf16x8 av[F], bv[F];
        #pragma unroll
        for (int i = 0; i < F; ++i)
            av[i] = *(const bf16x8*)&As[cur][(q * T + wr + i * 16 + r) * 8];
        #pragma unroll
        for (int j = 0; j < F; ++j)
            bv[j] = *(const bf16x8*)&Bs[cur][(q * T + wc + j * 16 + r) * 8];
        #pragma unroll
        for (int i = 0; i < F; ++i)
            #pragma unroll
            for (int j = 0; j < F; ++j)
                acc[i][j] = __builtin_amdgcn_mfma_f32_16x16x32_bf16(av[i], bv[j], acc[i][j], 0, 0, 0);

        // all waves done reading buf[cur] before next iter's prefetch overwrites it
        asm volatile("s_waitcnt lgkmcnt(0)" ::: "memory");
        asm volatile("s_barrier" ::: "memory");
    }

    // C layout: row = q*4 + reg, col = r (verified m89/m91)
    #pragma unroll
    for (int i = 0; i < F; ++i) {
        const int gr0 = m0 + wr + i * 16 + q * 4;
        #pragma unroll
        for (int j = 0; j < F; ++j) {
            const int gc = n0 + wc + j * 16 + r;
            const float bvl = bias ? bias[gc] : 0.0f;
            #pragma unroll
            for (int rr = 0; rr < 4; ++rr) {
                const long cidx = offC + (long)(gr0 + rr) * ldc + gc;
                float v = acc[i][j][rr] + bvl;
                if (mode == 0) {
                    Cf[cidx] = v;
                } else if (mode == 1) {
                    Cf[cidx] += v;
                } else if (mode == 2) {
                    Cb[cidx] = f2b(v);
                } else {
                    Cb[cidx] = f2b(0.5f * v * (1.0f + erff(v * 0.70710678118654752f)));
                }
            }
        }
    }
}

// fp32 [R][C] -> bf16 [C][R], 32x32 LDS tile transpose
__global__ void transpose_cast_f32(const float* __restrict__ in, unsigned short* __restrict__ out,
                                   int R, int C)
{
    __shared__ float t[32][33];
    const int c0 = blockIdx.x * 32, r0 = blockIdx.y * 32;
    const int tx = threadIdx.x, ty = threadIdx.y;
    #pragma unroll
    for (int i = 0; i < 4; ++i)
        t[ty + i * 8][tx] = in[(long)(r0 + ty + i * 8) * C + c0 + tx];
    __syncthreads();
    #pragma unroll
    for (int i = 0; i < 4; ++i)
        out[(long)(c0 + ty + i * 8) * R + r0 + tx] = f2b(t[tx][ty + i * 8]);
}

// V slice of qkv_b [2048][3072] (cols 2048 + h*256 + d) -> vT [h][d][m]
__global__ void transpose_v(const unsigned short* __restrict__ qkv, unsigned short* __restrict__ vT)
{
    __shared__ unsigned short t[32][33];
    const int hh = blockIdx.z;
    const int d0 = blockIdx.x * 32, m0 = blockIdx.y * 32;
    const int tx = threadIdx.x, ty = threadIdx.y;
    const unsigned short* ip = qkv + 2048 + hh * 256;
    unsigned short* op = vT + (long)hh * 524288;
    #pragma unroll
    for (int i = 0; i < 4; ++i)
        t[ty + i * 8][tx] = ip[(long)(m0 + ty + i * 8) * 3072 + d0 + tx];
    __syncthreads();
    #pragma unroll
    for (int i = 0; i < 4; ++i)
        op[(long)(d0 + ty + i * 8) * 2048 + m0 + tx] = t[tx][ty + i * 8];
}

__global__ void cast_f32_bf16(const float* __restrict__ in, unsigned short* __restrict__ out)
{
    const long i = (long)blockIdx.x * 256 + threadIdx.x;   // one float4 each
    const float4 v = ((const float4*)in)[i];
    ushort4v o;
    o[0] = f2b(v.x); o[1] = f2b(v.y); o[2] = f2b(v.z); o[3] = f2b(v.w);
    ((ushort4v*)out)[i] = o;
}

__global__ void zero_f32(float* __restrict__ p)
{
    p[blockIdx.x * 256 + threadIdx.x] = 0.0f;
}

// LayerNorm over D=1024, one block per token, writes bf16
__global__ __launch_bounds__(256) void ln_kernel(const float* __restrict__ h,
    const float* __restrict__ g, const float* __restrict__ bta,
    unsigned short* __restrict__ out)
{
    const int tok = blockIdx.x;
    const float4 v = ((const float4*)(h + (long)tok * 1024))[threadIdx.x];
    float s  = v.x + v.y + v.z + v.w;
    float s2 = v.x * v.x + v.y * v.y + v.z * v.z + v.w * v.w;
    #pragma unroll
    for (int off = 32; off > 0; off >>= 1) {
        s  += __shfl_xor(s, off);
        s2 += __shfl_xor(s2, off);
    }
    __shared__ float rs[4], rs2[4];
    const int wid = threadIdx.x >> 6, lane = threadIdx.x & 63;
    if (lane == 0) { rs[wid] = s; rs2[wid] = s2; }
    __syncthreads();
    s  = rs[0] + rs[1] + rs[2] + rs[3];
    s2 = rs2[0] + rs2[1] + rs2[2] + rs2[3];
    const float mu = s * (1.0f / 1024.0f);
    float var = s2 * (1.0f / 1024.0f) - mu * mu;
    var = fmaxf(var, 0.0f);
    const float rsg = 1.0f / sqrtf(var + 1e-5f);
    const float4 gv = ((const float4*)g)[threadIdx.x];
    const float4 bv = ((const float4*)bta)[threadIdx.x];
    ushort4v o;
    o[0] = f2b((v.x - mu) * rsg * gv.x + bv.x);
    o[1] = f2b((v.y - mu) * rsg * gv.y + bv.y);
    o[2] = f2b((v.z - mu) * rsg * gv.z + bv.z);
    o[3] = f2b((v.w - mu) * rsg * gv.w + bv.w);
    *(ushort4v*)&out[(long)tok * 1024 + threadIdx.x * 4] = o;
}

// RoPE in-place on bf16 qkv_b [2048][3072] (q: 0..1023, k: 1024..2047)
__global__ __launch_bounds__(256) void rope_kernel(unsigned short* __restrict__ qkv,
                                                   const int* __restrict__ pos)
{
    const int tok = blockIdx.x;
    const float p = (float)pos[tok];
    unsigned short* base = qkv + (long)tok * 3072;
    #pragma unroll
    for (int it = 0; it < 2; ++it) {
        const int idx = threadIdx.x + it * 256;  // (head, d<128)
        const int hh = idx >> 7, d = idx & 127;
        const float inv = powf(10000.0f, -(float)d * (1.0f / 128.0f));
        const float ang = p * inv;
        const float c = cosf(ang), s = sinf(ang);
        unsigned short* qp = base + hh * 256 + d;
        {
            const float x1 = b2f(qp[0]), x2 = b2f(qp[128]);
            qp[0]   = f2b(x1 * c - x2 * s);
            qp[128] = f2b(x1 * s + x2 * c);
        }
        unsigned short* kp = qp + 1024;
        {
            const float x1 = b2f(kp[0]), x2 = b2f(kp[128]);
            kp[0]   = f2b(x1 * c - x2 * s);
            kp[128] = f2b(x1 * s + x2 * c);
        }
    }
}

// Row softmax, in-place bf16, scale 1/16; mrow is this batch's mask row.
__global__ __launch_bounds__(256) void softmax_kernel(unsigned short* __restrict__ sc,
                                                      const float* __restrict__ mrow)
{
    unsigned short* row = sc + (long)blockIdx.x * 2048;
    const int t = threadIdx.x;

    float v[8];
    const ushort4v u0 = *(const ushort4v*)&row[t * 8];
    const ushort4v u1 = *(const ushort4v*)&row[t * 8 + 4];
    #pragma unroll
    for (int i = 0; i < 4; ++i) { v[i] = b2f(u0[i]); v[4 + i] = b2f(u1[i]); }

    float mx = -3.0e38f;
    #pragma unroll
    for (int i = 0; i < 8; ++i) {
        const float m = mrow[t * 8 + i];
        v[i] = (m == 0.0f) ? -3.0e38f : v[i] * 0.0625f;
        mx = fmaxf(mx, v[i]);
    }
    #pragma unroll
    for (int off = 32; off > 0; off >>= 1) mx = fmaxf(mx, __shfl_xor(mx, off));
    __shared__ float rmx[4], rsm[4];
    const int wid = t >> 6, lane = t & 63;
    if (lane == 0) rmx[wid] = mx;
    __syncthreads();
    mx = fmaxf(fmaxf(rmx[0], rmx[1]), fmaxf(rmx[2], rmx[3]));

    float s = 0.0f;
    #pragma unroll
    for (int i = 0; i < 8; ++i) { v[i] = expf(v[i] - mx); s += v[i]; }
    #pragma unroll
    for (int off = 32; off > 0; off >>= 1) s += __shfl_xor(s, off);
    if (lane == 0) rsm[wid] = s;
    __syncthreads();
    s = rsm[0] + rsm[1] + rsm[2] + rsm[3];
    const float invs = (s > 0.0f) ? 1.0f / s : 0.0f;

    ushort4v o0, o1;
    #pragma unroll
    for (int i = 0; i < 4; ++i) { o0[i] = f2b(v[i] * invs); o1[i] = f2b(v[4 + i] * invs); }
    *(ushort4v*)&row[t * 8]     = o0;
    *(ushort4v*)&row[t * 8 + 4] = o1;
}

// lengths = sum(mask[b]); out[b] = len>0 ? h[b, len-1] : start_state
__global__ __launch_bounds__(256) void gather_kernel(const float* __restrict__ h,
    const float* __restrict__ mask, const float* __restrict__ ss, float* __restrict__ out)
{
    const int b = blockIdx.x;
    const float* mrow = mask + b * 2048;
    const int t = threadIdx.x;
    float s = 0.0f;
    #pragma unroll
    for (int i = 0; i < 8; ++i) s += mrow[t * 8 + i];
    #pragma unroll
    for (int off = 32; off > 0; off >>= 1) s += __shfl_xor(s, off);
    __shared__ float red[4];
    if ((t & 63) == 0) red[t >> 6] = s;
    __syncthreads();
    const float len = red[0] + red[1] + red[2] + red[3];
    const int L = (int)len;
    const int last = (L > 0) ? (L - 1) : 0;
    const bool has = len > 0.0f;
    const float* src = has ? (h + ((long)b * 2048 + last) * 1024) : ss;
    #pragma unroll
    for (int i = 0; i < 4; ++i) {
        const int d = t + i * 256;
        out[b * 1024 + d] = src[d];
    }
}

// ---------------------------------------------------------------------------
extern "C" void kernel_launch(void* const* d_in, const int* in_sizes, int n_in,
                              void* d_out, int out_size, void* d_ws, size_t ws_size,
                              hipStream_t stream)
{
    (void)in_sizes; (void)n_in; (void)out_size;
    const float* x      = (const float*)d_in[0];
    const int*   pos    = (const int*)d_in[1];
    const float* mask   = (const float*)d_in[2];
    const float* in_w   = (const float*)d_in[3];
    const float* in_b   = (const float*)d_in[4];
    const float* qkv_w  = (const float*)d_in[5];
    const float* o_w    = (const float*)d_in[6];
    const float* ln1_g  = (const float*)d_in[7];
    const float* ln1_b  = (const float*)d_in[8];
    const float* ffn_w1 = (const float*)d_in[9];
    const float* ffn_b1 = (const float*)d_in[10];
    const float* ffn_w2 = (const float*)d_in[11];
    const float* ffn_b2 = (const float*)d_in[12];
    const float* ln2_g  = (const float*)d_in[13];
    const float* ln2_b  = (const float*)d_in[14];
    const float* sstate = (const float*)d_in[15];
    float* out = (float*)d_out;

    // ---- workspace layout, 143.65 MB (proven safe in round 2) ----
    const size_t NEED = 143654912ull;
    if (ws_size < NEED) {
        zero_f32<<<16, 256, 0, stream>>>(out);
        return;
    }
    char* w = (char*)d_ws;
    unsigned short* wt_in  = (unsigned short*)(w);               // [1024][512]      1.0 MB
    unsigned short* wt_qkv = (unsigned short*)(w + 1048576);     // [3072][1024]/lyr 6.3 MB
    unsigned short* wt_o   = (unsigned short*)(w + 7340032);     // [1024][1024]/lyr 2.1 MB
    unsigned short* wt_f1  = (unsigned short*)(w + 9437184);     // [4096][1024]/lyr 8.4 MB
    unsigned short* wt_f2  = (unsigned short*)(w + 17825792);    // [1024][4096]/lyr 8.4 MB
    float*          hbuf   = (float*)(w + 26214400);             // [8192][1024] f32 33.5 MB
    unsigned short* xn_bf  = (unsigned short*)(w + 59768832);    // [8192][1024]     16.8 MB
    unsigned short* ao_bf  = (unsigned short*)(w + 76546048);    // [8192][1024]     16.8 MB
    unsigned short* qkv_b  = (unsigned short*)(w + 93323264);    // [2048][3072]/b   12.6 MB
    unsigned short* vT_b   = (unsigned short*)(w + 105906176);   // [4][256][2048]/b  4.2 MB
    unsigned short* scmid  = (unsigned short*)(w + 110100480);   // [4][2048][2048]  33.5 MB
    unsigned short* x_bf   = ao_bf;                              // [8192][512], dead before ao live
    // FFN mid [8192][4096] bf16 = 67.1 MB aliases [ao_bf .. end): ao/qkv_b/vT_b/scmid
    // are all dead during the FFN (attention of this layer fully consumed them).
    unsigned short* mid_bf = (unsigned short*)(w + 76546048);

    const dim3 tb(32, 8);

    transpose_cast_f32<<<dim3(32, 16), tb, 0, stream>>>(in_w, wt_in, 512, 1024);
    cast_f32_bf16<<<4096, 256, 0, stream>>>(x, x_bf);

    // h = x @ in_w + in_b   (f32)
    gemm_bf16<128><<<dim3(8, 64, 1), 256, 0, stream>>>(x_bf, wt_in, hbuf, nullptr, in_b,
        512, 512, 512, 1024, 1, 0, 0, 0, 0, 0, 0, 0);

    for (int l = 0; l < 2; ++l) {
        transpose_cast_f32<<<dim3(96, 32),  tb, 0, stream>>>(qkv_w  + (long)l * 3145728, wt_qkv, 1024, 3072);
        transpose_cast_f32<<<dim3(32, 32),  tb, 0, stream>>>(o_w    + (long)l * 1048576, wt_o,   1024, 1024);
        transpose_cast_f32<<<dim3(128, 32), tb, 0, stream>>>(ffn_w1 + (long)l * 4194304, wt_f1,  1024, 4096);
        transpose_cast_f32<<<dim3(32, 128), tb, 0, stream>>>(ffn_w2 + (long)l * 4194304, wt_f2,  4096, 1024);

        ln_kernel<<<8192, 256, 0, stream>>>(hbuf, ln1_g + l * 1024, ln1_b + l * 1024, xn_bf);

        for (int b = 0; b < 4; ++b) {
            // qkv_b = LN1(h)[b] @ qkv_w  (bf16) — 64-tile: 1536 blocks
            gemm_bf16<64><<<dim3(48, 32, 1), 256, 0, stream>>>(xn_bf + (long)b * 2097152, wt_qkv,
                nullptr, qkv_b, nullptr, 1024, 1024, 1024, 3072, 1, 0, 0, 0, 0, 0, 0, 2);
            rope_kernel<<<2048, 256, 0, stream>>>(qkv_b, pos + b * 2048);
            transpose_v<<<dim3(8, 64, 4), tb, 0, stream>>>(qkv_b, vT_b);
            // scores[h] = q @ k^T  (raw; softmax applies 1/16)
            gemm_bf16<128><<<dim3(16, 16, 4), 256, 0, stream>>>(qkv_b, qkv_b + 1024,
                nullptr, scmid, nullptr, 256, 3072, 3072, 2048,
                1, 256l, 0, 256l, 0, 4194304l, 0, 2);
            softmax_kernel<<<8192, 256, 0, stream>>>(scmid, mask + b * 2048);
            // ao[b][m][h*256+d] = P @ V — 64-tile: 512 blocks
            gemm_bf16<64><<<dim3(4, 32, 4), 256, 0, stream>>>(scmid, vT_b,
                nullptr, ao_bf + (long)b * 2097152, nullptr, 2048, 2048, 2048, 1024,
                1, 4194304l, 0, 524288l, 0, 256l, 0, 2);
        }
        // h += attn_out @ o_w
        gemm_bf16<128><<<dim3(8, 64, 1), 256, 0, stream>>>(ao_bf, wt_o,
            hbuf, nullptr, nullptr, 1024, 1024, 1024, 1024, 1, 0, 0, 0, 0, 0, 0, 1);

        ln_kernel<<<8192, 256, 0, stream>>>(hbuf, ln2_g + l * 1024, ln2_b + l * 1024, xn_bf);

        // mid = gelu(LN2(h) @ w1 + b1)  (bf16) — full M=8192: 2048 blocks
        gemm_bf16<128><<<dim3(32, 64, 1), 256, 0, stream>>>(xn_bf, wt_f1,
            nullptr, mid_bf, ffn_b1 + l * 4096, 1024, 1024, 1024, 4096, 1, 0, 0, 0, 0, 0, 0, 3);
        // h += mid @ w2 + b2 — full M=8192: 512 blocks
        gemm_bf16<128><<<dim3(8, 64, 1), 256, 0, stream>>>(mid_bf, wt_f2,
            hbuf, nullptr, ffn_b2 + l * 1024, 4096, 4096, 4096, 1024, 1, 0, 0, 0, 0, 0, 0, 1);
    }

    gather_kernel<<<4, 256, 0, stream>>>(hbuf, mask, sstate, out);
}